// Round 3
// baseline (1450.570 us; speedup 1.0000x reference)
//
#include <hip/hip_runtime.h>
#include <hip/hip_bf16.h>
#include <hip/hip_cooperative_groups.h>

namespace cg = cooperative_groups;

#define N_NODES 50000
#define N_EDGES 800000
#define IN_N    256
#define D       64
#define NBLK    1024
#define NTHR    256
#define NCHUNK  1021          // ceil(50000/49)

typedef __attribute__((ext_vector_type(8))) short short8;
typedef __attribute__((ext_vector_type(4))) float f32x4;

__device__ __forceinline__ float bf2f(unsigned short h) {
    union { unsigned int u; float f; } x; x.u = ((unsigned int)h) << 16; return x.f;
}
__device__ __forceinline__ unsigned short f2bf(float f) {
    union { float f; unsigned int u; } x; x.f = f;
    unsigned int r = x.u + 0x7fff + ((x.u >> 16) & 1);   // RNE
    return (unsigned short)(r >> 16);
}
__device__ __forceinline__ short8 pack8(f32x4 p0, f32x4 p1) {
    short8 r;
    r[0] = (short)f2bf(p0[0]); r[1] = (short)f2bf(p0[1]);
    r[2] = (short)f2bf(p0[2]); r[3] = (short)f2bf(p0[3]);
    r[4] = (short)f2bf(p1[0]); r[5] = (short)f2bf(p1[1]);
    r[6] = (short)f2bf(p1[2]); r[7] = (short)f2bf(p1[3]);
    return r;
}

// ---------- phase bodies (shared by fused cooperative kernel and fallback) ----------

__device__ __forceinline__ void ph_zero_prep(int gtid, int gsz,
    const float* __restrict__ W_fc, const float* __restrict__ W_e,
    unsigned short* __restrict__ Wz, unsigned short* __restrict__ Wu,
    unsigned short* __restrict__ Wv, int* __restrict__ count)
{
    for (int i = gtid; i < N_NODES; i += gsz) count[i] = 0;
    // Wz = bf16(W_fc); Wu = bf16(W1@W_fc); Wv = bf16(W3@W_fc)  (all [64][256])
    for (int f = gtid; f < 3 * 64 * 256; f += gsz) {
        int mat = f >> 14, idx = f & 16383;
        if (mat == 0) { Wz[idx] = f2bf(W_fc[idx]); continue; }
        int o = idx >> 8, i = idx & 255;
        const float* wrow = W_e + (size_t)o * 192 + (mat == 2 ? 128 : 0);
        float s = 0.f;
        #pragma unroll 8
        for (int j = 0; j < 64; ++j) s += wrow[j] * W_fc[(size_t)j * 256 + i];
        (mat == 1 ? Wu : Wv)[idx] = f2bf(s);
    }
}

__device__ __forceinline__ void ph_count(int gtid, int gsz,
    const int* __restrict__ dst, int* __restrict__ count)
{
    for (int i = gtid; i < N_EDGES / 4; i += gsz) {
        int4 d = ((const int4*)dst)[i];
        atomicAdd(&count[d.x], 1);
        atomicAdd(&count[d.y], 1);
        atomicAdd(&count[d.z], 1);
        atomicAdd(&count[d.w], 1);
    }
}

// per-chunk local exclusive scan (chunk = 49 nodes), wave 0 of each block
__device__ __forceinline__ void ph_scan_a(
    const int* __restrict__ count, int* __restrict__ cursor, int* __restrict__ partial)
{
    int chunk = blockIdx.x;
    if (chunk >= NCHUNK || threadIdx.x >= 64) return;
    int lane = threadIdx.x;
    int idx = chunk * 49 + lane;
    int val = (lane < 49 && idx < N_NODES) ? count[idx] : 0;
    int inc = val;
    #pragma unroll
    for (int st = 1; st < 64; st <<= 1) {
        int o = __shfl_up(inc, st, 64);
        if (lane >= st) inc += o;
    }
    if (lane < 49 && idx < N_NODES) cursor[idx] = inc - val;   // local exclusive
    if (lane == 63) partial[chunk] = inc;                       // chunk total
}

// scan of the 1021 chunk totals -> base[], block 0 wave 0 only
__device__ __forceinline__ void ph_scan_b(
    const int* __restrict__ partial, int* __restrict__ base)
{
    if (blockIdx.x != 0 || threadIdx.x >= 64) return;
    int lane = threadIdx.x;
    int vals[16]; int s = 0;
    #pragma unroll
    for (int k = 0; k < 16; ++k) {
        int idx = lane * 16 + k;
        int v = (idx < NCHUNK) ? partial[idx] : 0;
        vals[k] = v; s += v;
    }
    int inc = s;
    #pragma unroll
    for (int st = 1; st < 64; st <<= 1) {
        int o = __shfl_up(inc, st, 64);
        if (lane >= st) inc += o;
    }
    int run = inc - s;                                          // exclusive lane base
    #pragma unroll
    for (int k = 0; k < 16; ++k) {
        int idx = lane * 16 + k;
        if (idx < NCHUNK) base[idx] = run;
        run += vals[k];
    }
}

// cursor finalize: add chunk base -> cursor = global exclusive prefix (offsets)
__device__ __forceinline__ void ph_scan_c(int gtid, int gsz,
    int* __restrict__ cursor, const int* __restrict__ base)
{
    for (int i = gtid; i < N_NODES; i += gsz) cursor[i] += base[i / 49];
}

// fused node pass: z, u(+bias), v from one sweep of nfeats
__device__ __forceinline__ void ph_node(int wv, int nwv, int lanelo, int quad,
    const float* __restrict__ nf,
    const unsigned short* __restrict__ Wz, const unsigned short* __restrict__ Wu,
    const unsigned short* __restrict__ Wv, const float* __restrict__ b_e,
    unsigned short* __restrict__ z_bf, unsigned short* __restrict__ u_bf,
    unsigned short* __restrict__ v_bf)
{
    float bias[4];
    #pragma unroll
    for (int t = 0; t < 4; ++t) bias[t] = b_e[t * 16 + lanelo];
    const f32x4 z4 = {0.f, 0.f, 0.f, 0.f};
    for (int g = wv; g < N_NODES / 16; g += nwv) {
        const int n0 = g * 16;
        f32x4 az[4] = {z4, z4, z4, z4};
        f32x4 au[4] = {z4, z4, z4, z4};
        f32x4 av[4] = {z4, z4, z4, z4};
        const float* arow = nf + (size_t)(n0 + lanelo) * IN_N;
        #pragma unroll
        for (int h = 0; h < 8; ++h) {
            const float* ap = arow + h * 32 + quad * 8;
            f32x4 p0 = *(const f32x4*)ap;
            f32x4 p1 = *(const f32x4*)(ap + 4);
            short8 a = pack8(p0, p1);
            const int bo = h * 32 + quad * 8;
            #pragma unroll
            for (int t = 0; t < 4; ++t) {
                const size_t rb = (size_t)(t * 16 + lanelo) * 256 + bo;
                az[t] = __builtin_amdgcn_mfma_f32_16x16x32_bf16(a, *(const short8*)&Wz[rb], az[t], 0, 0, 0);
                au[t] = __builtin_amdgcn_mfma_f32_16x16x32_bf16(a, *(const short8*)&Wu[rb], au[t], 0, 0, 0);
                av[t] = __builtin_amdgcn_mfma_f32_16x16x32_bf16(a, *(const short8*)&Wv[rb], av[t], 0, 0, 0);
            }
        }
        #pragma unroll
        for (int t = 0; t < 4; ++t)
            #pragma unroll
            for (int r = 0; r < 4; ++r) {
                const size_t row = (size_t)(n0 + quad * 4 + r) * D + t * 16 + lanelo;
                z_bf[row] = f2bf(az[t][r]);
                u_bf[row] = f2bf(au[t][r] + bias[t]);
                v_bf[row] = f2bf(av[t][r]);
            }
    }
}

// fused edge pass: t = W2@efeat; f = leaky(t+u[src]+v[dst]); feat_out = f;
// ex = exp(dot(f,w_c)); scatter {ex,src} to dst-ordered CSR slot (1 atomic/edge)
__device__ __forceinline__ void ph_edge(int wv, int nwv, int lanelo, int quad,
    const float* __restrict__ efeats,
    const int* __restrict__ src, const int* __restrict__ dst,
    const float* __restrict__ W_e, const float* __restrict__ w_c,
    const unsigned short* __restrict__ u_bf, const unsigned short* __restrict__ v_bf,
    int* __restrict__ cursor, unsigned long long* __restrict__ csr,
    float* __restrict__ feat_out)
{
    short8 b2[4][2];
    #pragma unroll
    for (int t = 0; t < 4; ++t)
        #pragma unroll
        for (int h = 0; h < 2; ++h)
            #pragma unroll
            for (int j = 0; j < 8; ++j)
                b2[t][h][j] = (short)f2bf(W_e[(size_t)(t * 16 + lanelo) * 192 + 64 + h * 32 + quad * 8 + j]);
    float wcv[4];
    #pragma unroll
    for (int t = 0; t < 4; ++t) wcv[t] = w_c[t * 16 + lanelo];

    const f32x4 z4 = {0.f, 0.f, 0.f, 0.f};
    for (int g = wv; g < N_EDGES / 16; g += nwv) {
        const int e0 = g * 16;
        f32x4 acc[4] = {z4, z4, z4, z4};
        const float* ar = efeats + (size_t)(e0 + lanelo) * D;
        #pragma unroll
        for (int h = 0; h < 2; ++h) {
            f32x4 p0 = __builtin_nontemporal_load((const f32x4*)(ar + h * 32 + quad * 8));
            f32x4 p1 = __builtin_nontemporal_load((const f32x4*)(ar + h * 32 + quad * 8 + 4));
            short8 a = pack8(p0, p1);
            #pragma unroll
            for (int t = 0; t < 4; ++t)
                acc[t] = __builtin_amdgcn_mfma_f32_16x16x32_bf16(a, b2[t][h], acc[t], 0, 0, 0);
        }
        int sn[4], dn[4];
        #pragma unroll
        for (int r = 0; r < 4; ++r) {
            sn[r] = src[e0 + quad * 4 + r];
            dn[r] = dst[e0 + quad * 4 + r];
        }
        float part[4];
        #pragma unroll
        for (int r = 0; r < 4; ++r) {
            float p = 0.f;
            #pragma unroll
            for (int t = 0; t < 4; ++t) {
                float f = acc[t][r]
                        + bf2f(u_bf[(size_t)sn[r] * D + t * 16 + lanelo])
                        + bf2f(v_bf[(size_t)dn[r] * D + t * 16 + lanelo]);
                f = f > 0.f ? f : 0.01f * f;
                __builtin_nontemporal_store(f, &feat_out[(size_t)(e0 + quad * 4 + r) * D + t * 16 + lanelo]);
                p += f * wcv[t];
            }
            part[r] = p;
        }
        #pragma unroll
        for (int st = 1; st < 16; st <<= 1) {
            #pragma unroll
            for (int r = 0; r < 4; ++r) part[r] += __shfl_xor(part[r], st, 64);
        }
        #pragma unroll
        for (int r = 0; r < 4; ++r) {
            float ex = __expf(part[r]);
            if (lanelo == 0) {
                int pos = atomicAdd(&cursor[dn[r]], 1);
                csr[pos] = ((unsigned long long)__float_as_uint(ex) << 32)
                         | (unsigned long long)(unsigned int)sn[r];
            }
        }
    }
}

// gather aggregation. After edge: cursor[n] == offsets[n+1]; start = cursor[n-1].
__device__ __forceinline__ void ph_agg(int wv, int nwv,
    const unsigned long long* __restrict__ csr, const int* __restrict__ cursor,
    const unsigned short* __restrict__ z_bf, float* __restrict__ h)
{
    const int lane = threadIdx.x & 63;
    for (int n = wv; n < N_NODES; n += nwv) {
        int beg = (n == 0) ? 0 : cursor[n - 1];
        int end = cursor[n];
        float acc = 0.f, ssum = 0.f;
        for (int j = beg; j < end; j += 8) {        // 8 gathers in flight
            #pragma unroll
            for (int k = 0; k < 8; ++k) {
                int jj = j + k;
                if (jj < end) {
                    unsigned long long p = csr[jj];
                    float x = __uint_as_float((unsigned int)(p >> 32));
                    int sidx = (int)(p & 0xffffffffu);
                    acc += x * bf2f(z_bf[(size_t)sidx * D + lane]);
                    ssum += x;
                }
            }
        }
        __builtin_nontemporal_store(ssum > 0.f ? acc / ssum : 0.f, &h[(size_t)n * D + lane]);
    }
}

// ---------- fused cooperative kernel ----------

__global__ void __launch_bounds__(NTHR, 4) fused_all(
    const float* nfeats, const float* efeats, const int* src, const int* dst,
    const float* W_fc, const float* W_e, const float* b_e, const float* w_c,
    unsigned short* z_bf, unsigned short* u_bf, unsigned short* v_bf,
    unsigned long long* csr, unsigned short* Wz, unsigned short* Wu, unsigned short* Wv,
    int* count, int* cursor, int* partial, int* baseArr,
    float* h_out, float* f_out)
{
    cg::grid_group grid = cg::this_grid();
    const int gtid = blockIdx.x * NTHR + threadIdx.x;
    const int gsz  = gridDim.x * NTHR;
    const int wv = gtid >> 6, nwv = gsz >> 6;
    const int lanelo = threadIdx.x & 15, quad = (threadIdx.x >> 4) & 3;

    ph_zero_prep(gtid, gsz, W_fc, W_e, Wz, Wu, Wv, count);
    grid.sync();
    ph_count(gtid, gsz, dst, count);
    grid.sync();
    ph_scan_a(count, cursor, partial);
    grid.sync();
    ph_scan_b(partial, baseArr);
    grid.sync();
    ph_scan_c(gtid, gsz, cursor, baseArr);                       // cursor = offsets
    ph_node(wv, nwv, lanelo, quad, nfeats, Wz, Wu, Wv, b_e, z_bf, u_bf, v_bf);
    grid.sync();
    ph_edge(wv, nwv, lanelo, quad, efeats, src, dst, W_e, w_c, u_bf, v_bf,
            cursor, csr, f_out);
    grid.sync();
    ph_agg(wv, nwv, csr, cursor, z_bf, h_out);
}

// ---------- fallback plain kernels (used only if cooperative launch fails) ----------

__global__ void __launch_bounds__(NTHR) k_zero_prep(const float* W_fc, const float* W_e,
    unsigned short* Wz, unsigned short* Wu, unsigned short* Wv, int* count) {
    ph_zero_prep(blockIdx.x * NTHR + threadIdx.x, gridDim.x * NTHR, W_fc, W_e, Wz, Wu, Wv, count);
}
__global__ void __launch_bounds__(NTHR) k_count(const int* dst, int* count) {
    ph_count(blockIdx.x * NTHR + threadIdx.x, gridDim.x * NTHR, dst, count);
}
__global__ void __launch_bounds__(NTHR) k_scan_a(const int* count, int* cursor, int* partial) {
    ph_scan_a(count, cursor, partial);
}
__global__ void __launch_bounds__(NTHR) k_scan_b(const int* partial, int* base) {
    ph_scan_b(partial, base);
}
__global__ void __launch_bounds__(NTHR) k_scan_c(int* cursor, const int* base) {
    ph_scan_c(blockIdx.x * NTHR + threadIdx.x, gridDim.x * NTHR, cursor, base);
}
__global__ void __launch_bounds__(NTHR) k_node(const float* nf,
    const unsigned short* Wz, const unsigned short* Wu, const unsigned short* Wv,
    const float* b_e, unsigned short* z_bf, unsigned short* u_bf, unsigned short* v_bf) {
    int gtid = blockIdx.x * NTHR + threadIdx.x;
    ph_node(gtid >> 6, (gridDim.x * NTHR) >> 6, threadIdx.x & 15, (threadIdx.x >> 4) & 3,
            nf, Wz, Wu, Wv, b_e, z_bf, u_bf, v_bf);
}
__global__ void __launch_bounds__(NTHR) k_edge(const float* efeats, const int* src, const int* dst,
    const float* W_e, const float* w_c, const unsigned short* u_bf, const unsigned short* v_bf,
    int* cursor, unsigned long long* csr, float* feat_out) {
    int gtid = blockIdx.x * NTHR + threadIdx.x;
    ph_edge(gtid >> 6, (gridDim.x * NTHR) >> 6, threadIdx.x & 15, (threadIdx.x >> 4) & 3,
            efeats, src, dst, W_e, w_c, u_bf, v_bf, cursor, csr, feat_out);
}
__global__ void __launch_bounds__(NTHR) k_agg(const unsigned long long* csr, const int* cursor,
    const unsigned short* z_bf, float* h) {
    int gtid = blockIdx.x * NTHR + threadIdx.x;
    ph_agg(gtid >> 6, (gridDim.x * NTHR) >> 6, csr, cursor, z_bf, h);
}

extern "C" void kernel_launch(void* const* d_in, const int* in_sizes, int n_in,
                              void* d_out, int out_size, void* d_ws, size_t ws_size,
                              hipStream_t stream)
{
    const float* nfeats = (const float*)d_in[0];
    const float* efeats = (const float*)d_in[1];
    const int* src = (const int*)d_in[2];
    const int* dst = (const int*)d_in[3];
    const float* W_fc = (const float*)d_in[4];
    const float* W_e  = (const float*)d_in[5];
    const float* b_e  = (const float*)d_in[6];
    const float* w_c  = (const float*)d_in[7];

    // ws layout: z|u|v (bf16 6.4MB each) | csr 6.4MB | Wz|Wu|Wv (32KB each) |
    //            count[N] | cursor[N] | partial[NCHUNK] | base[NCHUNK]
    unsigned short* z_bf = (unsigned short*)d_ws;
    unsigned short* u_bf = z_bf + (size_t)N_NODES * D;
    unsigned short* v_bf = u_bf + (size_t)N_NODES * D;
    unsigned long long* csr = (unsigned long long*)(v_bf + (size_t)N_NODES * D);
    unsigned short* Wz = (unsigned short*)(csr + (size_t)N_EDGES);
    unsigned short* Wu = Wz + 64 * 256;
    unsigned short* Wv = Wu + 64 * 256;
    int* count   = (int*)(Wv + 64 * 256);
    int* cursor  = count + N_NODES;
    int* partial = cursor + N_NODES;
    int* baseArr = partial + NCHUNK;

    float* h_out = (float*)d_out;
    float* f_out = h_out + (size_t)N_NODES * D;

    void* args[] = {
        (void*)&nfeats, (void*)&efeats, (void*)&src, (void*)&dst,
        (void*)&W_fc, (void*)&W_e, (void*)&b_e, (void*)&w_c,
        (void*)&z_bf, (void*)&u_bf, (void*)&v_bf, (void*)&csr,
        (void*)&Wz, (void*)&Wu, (void*)&Wv,
        (void*)&count, (void*)&cursor, (void*)&partial, (void*)&baseArr,
        (void*)&h_out, (void*)&f_out
    };
    hipError_t err = hipLaunchCooperativeKernel((void*)fused_all,
        dim3(NBLK), dim3(NTHR), args, 0, stream);
    if (err != hipSuccess) {
        // fallback: plain dispatch chain (correct, just more launch overhead)
        k_zero_prep<<<NBLK, NTHR, 0, stream>>>(W_fc, W_e, Wz, Wu, Wv, count);
        k_count<<<NBLK, NTHR, 0, stream>>>(dst, count);
        k_scan_a<<<NBLK, NTHR, 0, stream>>>(count, cursor, partial);
        k_scan_b<<<1, NTHR, 0, stream>>>(partial, baseArr);
        k_scan_c<<<NBLK, NTHR, 0, stream>>>(cursor, baseArr);
        k_node<<<NBLK, NTHR, 0, stream>>>(nfeats, Wz, Wu, Wv, b_e, z_bf, u_bf, v_bf);
        k_edge<<<2048, NTHR, 0, stream>>>(efeats, src, dst, W_e, w_c, u_bf, v_bf,
                                          cursor, csr, f_out);
        k_agg<<<2048, NTHR, 0, stream>>>(csr, cursor, z_bf, h_out);
    }
}